// Round 3
// baseline (1237.441 us; speedup 1.0000x reference)
//
#include <hip/hip_runtime.h>

typedef unsigned int uint;

#define K_SEL   13107u
#define BATCH   256
#define UNITS   131072
#define HB      4096      // 12-bit first-stage bins
#define CAP     6144      // candidate capacity per row (expect ~2800)

// ---------- workspace layout (bytes) ----------
// 0         boost   [131072] f32          524288
// 524288    ghist   [256][4096] u32      4194304   (memset)
// 4718592   candcnt [256] u32               1024   (memset, contiguous with ghist)
// 4719616   b1      [256] u32               1024
// 4720640   prior   [256] u32               1024
// 4721664   candkey [256][CAP] u32        6291456
// 11013120  candidx [256][CAP] u32        6291456
// 17304576  cnt4    [4][131072] u32       2097152
// total 19401728 (~18.5 MB)

__device__ __forceinline__ uint tokey(float f) {
    uint b = __float_as_uint(f);
    return b ^ ((uint)((int)b >> 31) | 0x80000000u);
}

__global__ void boost_kernel(const float* __restrict__ duty, float* __restrict__ boost) {
    int u = blockIdx.x * 256 + threadIdx.x;
    const float TARGET = (float)(13107.0 / 131072.0);
    float t = __fsub_rn(TARGET, duty[u]);
    boost[u] = (float)exp((double)t);   // correctly-rounded f32, matches np.exp
}

// Full-BW streaming histogram: 4 chunk-blocks per row, per-row 4096-bin key-prefix hist.
__global__ __launch_bounds__(256) void hist_kernel(const float* __restrict__ in,
                                                   const float* __restrict__ boost,
                                                   uint* __restrict__ ghist) {
    __shared__ uint lh[2][HB];    // 2 replicas, 2 waves each
    const int row = blockIdx.y;
    uint* h = lh[(threadIdx.x >> 7) & 1];
    for (int i = threadIdx.x; i < 2 * HB; i += 256) ((uint*)lh)[i] = 0u;
    __syncthreads();

    const float4* inp = (const float4*)(in + (size_t)row * UNITS) + (size_t)blockIdx.x * 8192;
    const float4* bst = (const float4*)boost + (size_t)blockIdx.x * 8192;
    for (int i = 0; i < 32; i++) {
        int idx = i * 256 + threadIdx.x;
        float4 a = inp[idx];
        float4 b = bst[idx];
        atomicAdd(&h[tokey(a.x * b.x) >> 20], 1u);
        atomicAdd(&h[tokey(a.y * b.y) >> 20], 1u);
        atomicAdd(&h[tokey(a.z * b.z) >> 20], 1u);
        atomicAdd(&h[tokey(a.w * b.w) >> 20], 1u);
    }
    __syncthreads();
    uint* gh = ghist + (size_t)row * HB;
    for (int i = threadIdx.x; i < HB; i += 256) {
        uint s = lh[0][i] + lh[1][i];
        if (s) atomicAdd(&gh[i], s);
    }
}

// Per row: find crossing bin b1 (12-bit prefix) and prior = count of keys in higher bins.
__global__ __launch_bounds__(256) void scan_kernel(const uint* __restrict__ ghist,
                                                   uint* __restrict__ b1_a,
                                                   uint* __restrict__ prior_a) {
    __shared__ uint h[HB];
    __shared__ uint ts[256];
    __shared__ uint bc[2];
    const int row = blockIdx.x;
    const int tid = threadIdx.x;
    const uint* gh = ghist + (size_t)row * HB;
    for (int i = tid; i < HB; i += 256) h[i] = gh[i];
    __syncthreads();

    const int b0 = tid * 16;
    uint binsum[16];
    uint segsum = 0;
    for (int i = 0; i < 16; i++) { binsum[i] = h[b0 + i]; segsum += binsum[i]; }
    ts[tid] = segsum;
    __syncthreads();
    for (int off = 1; off < 256; off <<= 1) {
        uint v = (tid + off < 256) ? ts[tid + off] : 0u;
        __syncthreads();
        ts[tid] += v;
        __syncthreads();
    }
    uint cum = ts[tid] - segsum;   // count of keys in bins above my segment
    for (int i = 15; i >= 0; i--) {
        uint hb = binsum[i];
        uint c2 = cum + hb;
        if (cum < K_SEL && c2 >= K_SEL) { bc[0] = (uint)(b0 + i); bc[1] = cum; }
        cum = c2;
    }
    __syncthreads();
    if (tid == 0) { b1_a[row] = bc[0]; prior_a[row] = bc[1]; }
}

// Streaming apply: winners above the crossing bin written directly; crossing-bin
// elements compacted into per-row candidate lists (decided later by selectfix).
__global__ __launch_bounds__(256) void apply_kernel(const float* __restrict__ in,
                                                    const float* __restrict__ boost,
                                                    const uint* __restrict__ b1_a,
                                                    float* __restrict__ out,
                                                    uint* __restrict__ cnt4,
                                                    uint* __restrict__ candcnt,
                                                    uint* __restrict__ candkey,
                                                    uint* __restrict__ candidx) {
    __shared__ uint s_b1[64];
    const int r0 = blockIdx.y * 64;
    if (threadIdx.x < 64) s_b1[threadIdx.x] = b1_a[r0 + threadIdx.x];
    __syncthreads();

    const int c4 = blockIdx.x * 256 + threadIdx.x;
    const float4 bst = ((const float4*)boost)[c4];
    const uint u0 = (uint)c4 * 4u;
    const float bb[4] = {bst.x, bst.y, bst.z, bst.w};
    uint cnt[4] = {0u, 0u, 0u, 0u};

    for (int r = 0; r < 64; r++) {
        const int row = r0 + r;
        const float4 v = ((const float4*)(in + (size_t)row * UNITS))[c4];
        const uint b1 = s_b1[r];
        const float vv[4] = {v.x, v.y, v.z, v.w};
        float o[4];
        #pragma unroll
        for (int c = 0; c < 4; c++) {
            const uint k = tokey(vv[c] * bb[c]);
            const uint kb = k >> 20;
            const bool hi = kb > b1;
            o[c] = hi ? vv[c] : 0.0f;
            cnt[c] += hi ? 1u : 0u;
            if (kb == b1) {
                uint p = atomicAdd(&candcnt[row], 1u);
                if (p < CAP) {
                    candkey[(size_t)row * CAP + p] = k;
                    candidx[(size_t)row * CAP + p] = u0 + (uint)c;
                }
            }
        }
        ((float4*)(out + (size_t)row * UNITS))[c4] = make_float4(o[0], o[1], o[2], o[3]);
    }
    ((uint4*)(cnt4 + (size_t)blockIdx.y * UNITS))[c4] = make_uint4(cnt[0], cnt[1], cnt[2], cnt[3]);
}

// 1024-bin suffix-scan crossing finder (shared helper; all 256 threads call).
__device__ __forceinline__ void find_cross_1024(const uint* __restrict__ h, uint* ts,
                                                uint need, uint* out3, int tid) {
    uint binsum[4];
    uint segsum = 0;
    const int b0 = tid * 4;
    for (int i = 0; i < 4; i++) { binsum[i] = h[b0 + i]; segsum += binsum[i]; }
    ts[tid] = segsum;
    __syncthreads();
    for (int off = 1; off < 256; off <<= 1) {
        uint v = (tid + off < 256) ? ts[tid + off] : 0u;
        __syncthreads();
        ts[tid] += v;
        __syncthreads();
    }
    uint cum = ts[tid] - segsum;
    for (int i = 3; i >= 0; i--) {
        uint hb = binsum[i];
        uint c2 = cum + hb;
        if (cum < need && c2 >= need) { out3[0] = (uint)(b0 + i); out3[1] = cum; out3[2] = hb; }
        cum = c2;
    }
    __syncthreads();
}

// Per row: exact 20-bit radix select over <=CAP candidates in LDS, tie-break by
// lowest index, then scatter winning values and duty counts.
__global__ __launch_bounds__(256) void selectfix_kernel(const float* __restrict__ in,
                                                        const uint* __restrict__ candcnt,
                                                        const uint* __restrict__ candkey,
                                                        const uint* __restrict__ candidx,
                                                        const uint* __restrict__ prior_a,
                                                        float* __restrict__ out,
                                                        uint* __restrict__ cnt4) {
    __shared__ uint kbuf[CAP];
    __shared__ uint h1[1024];
    __shared__ uint ts[256];
    __shared__ uint sh[6];
    const int row = blockIdx.x;
    const int tid = threadIdx.x;
    const uint n = min(candcnt[row], (uint)CAP);
    const uint needbin = K_SEL - prior_a[row];
    const uint* ck = candkey + (size_t)row * CAP;
    const uint* ci = candidx + (size_t)row * CAP;

    for (uint i = tid; i < n; i += 256) kbuf[i] = ck[i];
    const bool allwin = (needbin >= n);
    uint tk = 0, nd_eq = 0, eqc = 0;

    if (!allwin) {
        // round 1: bits 19:10
        for (int i = tid; i < 1024; i += 256) h1[i] = 0u;
        __syncthreads();
        for (uint i = tid; i < n; i += 256) atomicAdd(&h1[(kbuf[i] >> 10) & 1023u], 1u);
        __syncthreads();
        find_cross_1024(h1, ts, needbin, sh, tid);
        const uint b2 = sh[0];
        const uint need2 = needbin - sh[1];
        __syncthreads();
        // round 2: bits 9:0 among round-1 crossing bin
        for (int i = tid; i < 1024; i += 256) h1[i] = 0u;
        __syncthreads();
        for (uint i = tid; i < n; i += 256)
            if (((kbuf[i] >> 10) & 1023u) == b2) atomicAdd(&h1[kbuf[i] & 1023u], 1u);
        __syncthreads();
        find_cross_1024(h1, ts, need2, sh + 3, tid);
        const uint b3 = sh[3];
        tk = (kbuf[0] & 0xFFF00000u) | (b2 << 10) | b3;   // all keys share the 12-bit prefix
        nd_eq = need2 - sh[4];
        eqc = sh[5];
    } else {
        __syncthreads();
    }

    for (uint i = tid; i < n; i += 256) {
        const uint k = kbuf[i];
        bool win;
        if (allwin || k > tk) {
            win = true;
        } else if (k == tk) {
            if (eqc == nd_eq) {
                win = true;
            } else {                       // rare exact 32-bit tie: lowest-index-first
                const uint myidx = ci[i];
                uint rank = 0;
                for (uint j = 0; j < n; j++)
                    if (kbuf[j] == tk && ci[j] < myidx) rank++;
                win = rank < nd_eq;
            }
        } else {
            win = false;
        }
        if (win) {
            const uint idx = ci[i];
            out[(size_t)row * UNITS + idx] = in[(size_t)row * UNITS + idx];
            atomicAdd(&cnt4[idx], 1u);
        }
    }
}

__global__ void duty_kernel(const float* __restrict__ duty, const uint* __restrict__ cnt4,
                            float* __restrict__ out_duty) {
    int u = blockIdx.x * 256 + threadIdx.x;
    const float C1 = (float)(1.0 - 1.0 / 1000.0);
    const float C2 = (float)(1.0 / 1000.0);
    uint c = cnt4[u] + cnt4[UNITS + u] + cnt4[2 * UNITS + u] + cnt4[3 * UNITS + u];
    float cur = (float)c * (1.0f / 256.0f);   // exact
    out_duty[u] = __fadd_rn(__fmul_rn(C1, duty[u]), __fmul_rn(C2, cur));
}

extern "C" void kernel_launch(void* const* d_in, const int* in_sizes, int n_in,
                              void* d_out, int out_size, void* d_ws, size_t ws_size,
                              hipStream_t stream) {
    const float* inputs = (const float*)d_in[0];
    const float* duty   = (const float*)d_in[1];
    float* out      = (float*)d_out;
    float* out_duty = out + (size_t)BATCH * UNITS;

    char* ws = (char*)d_ws;
    float* boost  = (float*)(ws + 0);
    uint* ghist   = (uint*)(ws + 524288);
    uint* candcnt = (uint*)(ws + 4718592);
    uint* b1_a    = (uint*)(ws + 4719616);
    uint* prior_a = (uint*)(ws + 4720640);
    uint* candkey = (uint*)(ws + 4721664);
    uint* candidx = (uint*)(ws + 11013120);
    uint* cnt4    = (uint*)(ws + 17304576);

    hipMemsetAsync(ws + 524288, 0, 4195328, stream);   // ghist + candcnt

    boost_kernel<<<UNITS / 256, 256, 0, stream>>>(duty, boost);

    hist_kernel<<<dim3(4, BATCH), 256, 0, stream>>>(inputs, boost, ghist);

    scan_kernel<<<BATCH, 256, 0, stream>>>(ghist, b1_a, prior_a);

    apply_kernel<<<dim3(UNITS / 1024, 4), 256, 0, stream>>>(inputs, boost, b1_a, out, cnt4,
                                                            candcnt, candkey, candidx);

    selectfix_kernel<<<BATCH, 256, 0, stream>>>(inputs, candcnt, candkey, candidx,
                                                prior_a, out, cnt4);

    duty_kernel<<<UNITS / 256, 256, 0, stream>>>(duty, cnt4, out_duty);
}

// Round 4
// 313.994 us; speedup vs baseline: 3.9410x; 3.9410x over previous
//
#include <hip/hip_runtime.h>

typedef unsigned int uint;
typedef unsigned long long u64;

#define K_SEL   13107u
#define BATCH   256
#define UNITS   131072
#define HB      4096      // 12-bit first-stage bins
#define CAP     8192      // candidate capacity per row (expect ~2800)
#define NCHUNK  4

// ---------- workspace layout (bytes) ----------
// 0         boost   [131072] f32              524288
// 524288    ghist   [4][256][4096] u32      16777216   (fully rewritten each call)
// 17301504  candcnt [256][16] u32 (padded)      16384   (memset)
// 17317888  b1      [256] u32                    1024
// 17318912  prior   [256] u32                    1024
// 17319936  candkey [256][CAP] u32            8388608
// 25708544  candidx [256][CAP] u32            8388608
// 34097152  cnt4    [4][131072] u32           2097152
// total ~34.5 MB

__device__ __forceinline__ uint tokey(float f) {
    uint b = __float_as_uint(f);
    return b ^ ((uint)((int)b >> 31) | 0x80000000u);
}

__global__ void boost_kernel(const float* __restrict__ duty, float* __restrict__ boost) {
    int u = blockIdx.x * 256 + threadIdx.x;
    const float TARGET = (float)(13107.0 / 131072.0);
    float t = __fsub_rn(TARGET, duty[u]);
    boost[u] = (float)exp((double)t);   // correctly-rounded f32, matches np.exp
}

// Streaming histogram: per-(chunk,row) private 4096-bin slab, NO global atomics.
__global__ __launch_bounds__(256) void hist_kernel(const float* __restrict__ in,
                                                   const float* __restrict__ boost,
                                                   uint* __restrict__ ghist) {
    __shared__ uint lh[2][HB];    // 2 replicas (2 waves each)
    const int row = blockIdx.y;
    uint* h = lh[(threadIdx.x >> 7) & 1];
    for (int i = threadIdx.x; i < 2 * HB; i += 256) ((uint*)lh)[i] = 0u;
    __syncthreads();

    const float4* inp = (const float4*)(in + (size_t)row * UNITS) + (size_t)blockIdx.x * 8192;
    const float4* bst = (const float4*)boost + (size_t)blockIdx.x * 8192;
    for (int i = 0; i < 32; i++) {
        int idx = i * 256 + threadIdx.x;
        float4 a = inp[idx];
        float4 b = bst[idx];
        atomicAdd(&h[tokey(a.x * b.x) >> 20], 1u);
        atomicAdd(&h[tokey(a.y * b.y) >> 20], 1u);
        atomicAdd(&h[tokey(a.z * b.z) >> 20], 1u);
        atomicAdd(&h[tokey(a.w * b.w) >> 20], 1u);
    }
    __syncthreads();
    uint* gh = ghist + ((size_t)blockIdx.x * BATCH + row) * HB;
    for (int i = threadIdx.x; i < HB; i += 256) gh[i] = lh[0][i] + lh[1][i];
}

// Per row: sum 4 slabs, find crossing bin b1 and prior (count in higher bins).
__global__ __launch_bounds__(256) void scan_kernel(const uint* __restrict__ ghist,
                                                   uint* __restrict__ b1_a,
                                                   uint* __restrict__ prior_a) {
    __shared__ uint h[HB];
    __shared__ uint ts[256];
    __shared__ uint bc[2];
    const int row = blockIdx.x;
    const int tid = threadIdx.x;
    for (int i = tid; i < HB; i += 256) {
        uint s = 0;
        for (int c = 0; c < NCHUNK; c++) s += ghist[((size_t)c * BATCH + row) * HB + i];
        h[i] = s;
    }
    __syncthreads();

    const int b0 = tid * 16;
    uint binsum[16];
    uint segsum = 0;
    for (int i = 0; i < 16; i++) { binsum[i] = h[b0 + i]; segsum += binsum[i]; }
    ts[tid] = segsum;
    __syncthreads();
    for (int off = 1; off < 256; off <<= 1) {
        uint v = (tid + off < 256) ? ts[tid + off] : 0u;
        __syncthreads();
        ts[tid] += v;
        __syncthreads();
    }
    uint cum = ts[tid] - segsum;
    for (int i = 15; i >= 0; i--) {
        uint hb = binsum[i];
        uint c2 = cum + hb;
        if (cum < K_SEL && c2 >= K_SEL) { bc[0] = (uint)(b0 + i); bc[1] = cum; }
        cum = c2;
    }
    __syncthreads();
    if (tid == 0) { b1_a[row] = bc[0]; prior_a[row] = bc[1]; }
}

// Streaming apply: direct winners written; crossing-bin elements compacted via
// wave ballots + ONE atomic per wave per row (padded counters).
__global__ __launch_bounds__(256) void apply_kernel(const float* __restrict__ in,
                                                    const float* __restrict__ boost,
                                                    const uint* __restrict__ b1_a,
                                                    float* __restrict__ out,
                                                    uint* __restrict__ cnt4,
                                                    uint* __restrict__ candcnt,
                                                    uint* __restrict__ candkey,
                                                    uint* __restrict__ candidx) {
    __shared__ uint s_b1[64];
    const int r0 = blockIdx.y * 64;
    if (threadIdx.x < 64) s_b1[threadIdx.x] = b1_a[r0 + threadIdx.x];
    __syncthreads();

    const int lane = threadIdx.x & 63;
    const u64 ltmask = ((u64)1 << lane) - 1;
    const int c4 = blockIdx.x * 256 + threadIdx.x;
    const float4 bst = ((const float4*)boost)[c4];
    const uint u0 = (uint)c4 * 4u;
    const float bb[4] = {bst.x, bst.y, bst.z, bst.w};
    uint cnt[4] = {0u, 0u, 0u, 0u};

    for (int r = 0; r < 64; r++) {
        const int row = r0 + r;
        const float4 v = ((const float4*)(in + (size_t)row * UNITS))[c4];
        const uint b1 = s_b1[r];
        const float vv[4] = {v.x, v.y, v.z, v.w};
        float o[4];
        uint k[4];
        bool f[4];
        #pragma unroll
        for (int c = 0; c < 4; c++) {
            k[c] = tokey(vv[c] * bb[c]);
            const uint kb = k[c] >> 20;
            const bool hi = kb > b1;
            o[c] = hi ? vv[c] : 0.0f;
            cnt[c] += hi ? 1u : 0u;
            f[c] = (kb == b1);
        }
        ((float4*)(out + (size_t)row * UNITS))[c4] = make_float4(o[0], o[1], o[2], o[3]);

        u64 bal[4];
        #pragma unroll
        for (int c = 0; c < 4; c++) bal[c] = __ballot(f[c]);
        uint wtot = (uint)(__popcll(bal[0]) + __popcll(bal[1]) + __popcll(bal[2]) + __popcll(bal[3]));
        if (wtot) {   // wave-uniform
            uint sbase = 0;
            if (lane == 0) sbase = atomicAdd(&candcnt[row * 16], wtot);
            sbase = (uint)__shfl((int)sbase, 0);
            uint cum = 0;
            #pragma unroll
            for (int c = 0; c < 4; c++) {
                if (f[c]) {
                    uint pos = sbase + cum + (uint)__popcll(bal[c] & ltmask);
                    if (pos < CAP) {
                        candkey[(size_t)row * CAP + pos] = k[c];
                        candidx[(size_t)row * CAP + pos] = u0 + (uint)c;
                    }
                }
                cum += (uint)__popcll(bal[c]);
            }
        }
    }
    ((uint4*)(cnt4 + (size_t)blockIdx.y * UNITS))[c4] = make_uint4(cnt[0], cnt[1], cnt[2], cnt[3]);
}

// 1024-bin suffix-scan crossing finder (all 256 threads call).
__device__ __forceinline__ void find_cross_1024(const uint* __restrict__ h, uint* ts,
                                                uint need, uint* out3, int tid) {
    uint binsum[4];
    uint segsum = 0;
    const int b0 = tid * 4;
    for (int i = 0; i < 4; i++) { binsum[i] = h[b0 + i]; segsum += binsum[i]; }
    ts[tid] = segsum;
    __syncthreads();
    for (int off = 1; off < 256; off <<= 1) {
        uint v = (tid + off < 256) ? ts[tid + off] : 0u;
        __syncthreads();
        ts[tid] += v;
        __syncthreads();
    }
    uint cum = ts[tid] - segsum;
    for (int i = 3; i >= 0; i--) {
        uint hb = binsum[i];
        uint c2 = cum + hb;
        if (cum < need && c2 >= need) { out3[0] = (uint)(b0 + i); out3[1] = cum; out3[2] = hb; }
        cum = c2;
    }
    __syncthreads();
}

// Per row: exact 20-bit radix select over <=CAP candidates in LDS, lowest-index
// tie break, scatter winning values + duty counts.
__global__ __launch_bounds__(256) void selectfix_kernel(const float* __restrict__ in,
                                                        const uint* __restrict__ candcnt,
                                                        const uint* __restrict__ candkey,
                                                        const uint* __restrict__ candidx,
                                                        const uint* __restrict__ prior_a,
                                                        float* __restrict__ out,
                                                        uint* __restrict__ cnt4) {
    __shared__ uint kbuf[CAP];
    __shared__ uint h1[1024];
    __shared__ uint ts[256];
    __shared__ uint sh[6];
    const int row = blockIdx.x;
    const int tid = threadIdx.x;
    const uint n = min(candcnt[row * 16], (uint)CAP);
    const uint needbin = K_SEL - prior_a[row];
    const uint* ck = candkey + (size_t)row * CAP;
    const uint* ci = candidx + (size_t)row * CAP;

    for (uint i = tid; i < n; i += 256) kbuf[i] = ck[i];
    const bool allwin = (needbin >= n);
    uint tk = 0, nd_eq = 0, eqc = 0;

    if (!allwin) {
        for (int i = tid; i < 1024; i += 256) h1[i] = 0u;
        __syncthreads();
        for (uint i = tid; i < n; i += 256) atomicAdd(&h1[(kbuf[i] >> 10) & 1023u], 1u);
        __syncthreads();
        find_cross_1024(h1, ts, needbin, sh, tid);
        const uint b2 = sh[0];
        const uint need2 = needbin - sh[1];
        __syncthreads();
        for (int i = tid; i < 1024; i += 256) h1[i] = 0u;
        __syncthreads();
        for (uint i = tid; i < n; i += 256)
            if (((kbuf[i] >> 10) & 1023u) == b2) atomicAdd(&h1[kbuf[i] & 1023u], 1u);
        __syncthreads();
        find_cross_1024(h1, ts, need2, sh + 3, tid);
        const uint b3 = sh[3];
        tk = (kbuf[0] & 0xFFF00000u) | (b2 << 10) | b3;   // shared 12-bit prefix
        nd_eq = need2 - sh[4];
        eqc = sh[5];
    } else {
        __syncthreads();
    }

    for (uint i = tid; i < n; i += 256) {
        const uint k = kbuf[i];
        bool win;
        if (allwin || k > tk) {
            win = true;
        } else if (k == tk) {
            if (eqc == nd_eq) {
                win = true;
            } else {                       // rare exact 32-bit tie: lowest-index-first
                const uint myidx = ci[i];
                uint rank = 0;
                for (uint j = 0; j < n; j++)
                    if (kbuf[j] == tk && ci[j] < myidx) rank++;
                win = rank < nd_eq;
            }
        } else {
            win = false;
        }
        if (win) {
            const uint idx = ci[i];
            out[(size_t)row * UNITS + idx] = in[(size_t)row * UNITS + idx];
            atomicAdd(&cnt4[idx], 1u);
        }
    }
}

__global__ void duty_kernel(const float* __restrict__ duty, const uint* __restrict__ cnt4,
                            float* __restrict__ out_duty) {
    int u = blockIdx.x * 256 + threadIdx.x;
    const float C1 = (float)(1.0 - 1.0 / 1000.0);
    const float C2 = (float)(1.0 / 1000.0);
    uint c = cnt4[u] + cnt4[UNITS + u] + cnt4[2 * UNITS + u] + cnt4[3 * UNITS + u];
    float cur = (float)c * (1.0f / 256.0f);   // exact
    out_duty[u] = __fadd_rn(__fmul_rn(C1, duty[u]), __fmul_rn(C2, cur));
}

extern "C" void kernel_launch(void* const* d_in, const int* in_sizes, int n_in,
                              void* d_out, int out_size, void* d_ws, size_t ws_size,
                              hipStream_t stream) {
    const float* inputs = (const float*)d_in[0];
    const float* duty   = (const float*)d_in[1];
    float* out      = (float*)d_out;
    float* out_duty = out + (size_t)BATCH * UNITS;

    char* ws = (char*)d_ws;
    float* boost  = (float*)(ws + 0);
    uint* ghist   = (uint*)(ws + 524288);
    uint* candcnt = (uint*)(ws + 17301504);
    uint* b1_a    = (uint*)(ws + 17317888);
    uint* prior_a = (uint*)(ws + 17318912);
    uint* candkey = (uint*)(ws + 17319936);
    uint* candidx = (uint*)(ws + 25708544);
    uint* cnt4    = (uint*)(ws + 34097152);

    hipMemsetAsync(candcnt, 0, 16384, stream);

    boost_kernel<<<UNITS / 256, 256, 0, stream>>>(duty, boost);

    hist_kernel<<<dim3(NCHUNK, BATCH), 256, 0, stream>>>(inputs, boost, ghist);

    scan_kernel<<<BATCH, 256, 0, stream>>>(ghist, b1_a, prior_a);

    apply_kernel<<<dim3(UNITS / 1024, 4), 256, 0, stream>>>(inputs, boost, b1_a, out, cnt4,
                                                            candcnt, candkey, candidx);

    selectfix_kernel<<<BATCH, 256, 0, stream>>>(inputs, candcnt, candkey, candidx,
                                                prior_a, out, cnt4);

    duty_kernel<<<UNITS / 256, 256, 0, stream>>>(duty, cnt4, out_duty);
}

// Round 5
// 156.204 us; speedup vs baseline: 7.9219x; 2.0101x over previous
//
#include <hip/hip_runtime.h>

typedef unsigned int uint;
typedef unsigned long long u64;

#define K_SEL   13107u
#define BATCH   256
#define UNITS   131072
#define HB      4096      // 12-bit first-stage bins
#define CAP     8192      // candidate capacity per row (expect ~2800)
#define NCHUNK  4
#define EQLDS   2048      // max eq-key elements handled in LDS (far above any real case)
#define EQWIN   256       // max tie winners stored per row

#define MODE_ALL  0xFFFFFFFFu
#define MODE_SCAN 0xFFFFFFFEu

// ---------- workspace layout (bytes) ----------
// 0         boost   [131072] f32              524288
// 524288    ghist   [4][256][4096] u32      16777216  (fully rewritten)
// 17301504  candcnt [256][16] u32              16384  (memset)
// 17317888  b1      [256] u32                   1024
// 17318912  prior   [256] u32                   1024
// 17319936  tk_a    [256] u32                   1024
// 17320960  eqinfo  [256] u32                   1024
// 17321984  ndeq_a  [256] u32                   1024
// 17323008  eqwin   [256][EQWIN] u32          262144
// 17585152  candkey [256][CAP] u32           8388608
// 25973760  candidx [256][CAP] u32           8388608
// 34362368  cnt4    [4][131072] u32          2097152
// total 36459520 (~34.8 MB)

__device__ __forceinline__ uint tokey(float f) {
    uint b = __float_as_uint(f);
    return b ^ ((uint)((int)b >> 31) | 0x80000000u);
}

__global__ void boost_kernel(const float* __restrict__ duty, float* __restrict__ boost) {
    int u = blockIdx.x * 256 + threadIdx.x;
    const float TARGET = (float)(13107.0 / 131072.0);
    float t = __fsub_rn(TARGET, duty[u]);
    boost[u] = (float)exp((double)t);   // correctly-rounded f32, matches np.exp
}

// Streaming histogram: per-(chunk,row) private 4096-bin slab, NO global atomics.
__global__ __launch_bounds__(256) void hist_kernel(const float* __restrict__ in,
                                                   const float* __restrict__ boost,
                                                   uint* __restrict__ ghist) {
    __shared__ uint lh[2][HB];
    const int row = blockIdx.y;
    uint* h = lh[(threadIdx.x >> 7) & 1];
    for (int i = threadIdx.x; i < 2 * HB; i += 256) ((uint*)lh)[i] = 0u;
    __syncthreads();

    const float4* inp = (const float4*)(in + (size_t)row * UNITS) + (size_t)blockIdx.x * 8192;
    const float4* bst = (const float4*)boost + (size_t)blockIdx.x * 8192;
    for (int i = 0; i < 32; i++) {
        int idx = i * 256 + threadIdx.x;
        float4 a = inp[idx];
        float4 b = bst[idx];
        atomicAdd(&h[tokey(a.x * b.x) >> 20], 1u);
        atomicAdd(&h[tokey(a.y * b.y) >> 20], 1u);
        atomicAdd(&h[tokey(a.z * b.z) >> 20], 1u);
        atomicAdd(&h[tokey(a.w * b.w) >> 20], 1u);
    }
    __syncthreads();
    uint* gh = ghist + ((size_t)blockIdx.x * BATCH + row) * HB;
    for (int i = threadIdx.x; i < HB; i += 256) gh[i] = lh[0][i] + lh[1][i];
}

// Per row: sum 4 slabs, find crossing bin b1 and prior (count in higher bins).
__global__ __launch_bounds__(256) void scan_kernel(const uint* __restrict__ ghist,
                                                   uint* __restrict__ b1_a,
                                                   uint* __restrict__ prior_a) {
    __shared__ uint h[HB];
    __shared__ uint ts[256];
    __shared__ uint bc[2];
    const int row = blockIdx.x;
    const int tid = threadIdx.x;
    for (int i = tid; i < HB; i += 256) {
        uint s = 0;
        for (int c = 0; c < NCHUNK; c++) s += ghist[((size_t)c * BATCH + row) * HB + i];
        h[i] = s;
    }
    __syncthreads();

    const int b0 = tid * 16;
    uint binsum[16];
    uint segsum = 0;
    for (int i = 0; i < 16; i++) { binsum[i] = h[b0 + i]; segsum += binsum[i]; }
    ts[tid] = segsum;
    __syncthreads();
    for (int off = 1; off < 256; off <<= 1) {
        uint v = (tid + off < 256) ? ts[tid + off] : 0u;
        __syncthreads();
        ts[tid] += v;
        __syncthreads();
    }
    uint cum = ts[tid] - segsum;
    for (int i = 15; i >= 0; i--) {
        uint hb = binsum[i];
        uint c2 = cum + hb;
        if (cum < K_SEL && c2 >= K_SEL) { bc[0] = (uint)(b0 + i); bc[1] = cum; }
        cum = c2;
    }
    __syncthreads();
    if (tid == 0) { b1_a[row] = bc[0]; prior_a[row] = bc[1]; }
}

// Streaming apply: elements at-or-above the crossing bin keep their value and are
// counted as wins; crossing-bin elements additionally compacted (ballot + one
// atomic per wave per row). fixwrite later zeroes the losing candidates.
__global__ __launch_bounds__(256) void apply_kernel(const float* __restrict__ in,
                                                    const float* __restrict__ boost,
                                                    const uint* __restrict__ b1_a,
                                                    float* __restrict__ out,
                                                    uint* __restrict__ cnt4,
                                                    uint* __restrict__ candcnt,
                                                    uint* __restrict__ candkey,
                                                    uint* __restrict__ candidx) {
    __shared__ uint s_b1[64];
    const int r0 = blockIdx.y * 64;
    if (threadIdx.x < 64) s_b1[threadIdx.x] = b1_a[r0 + threadIdx.x];
    __syncthreads();

    const int lane = threadIdx.x & 63;
    const u64 ltmask = ((u64)1 << lane) - 1;
    const int c4 = blockIdx.x * 256 + threadIdx.x;
    const float4 bst = ((const float4*)boost)[c4];
    const uint u0 = (uint)c4 * 4u;
    const float bb[4] = {bst.x, bst.y, bst.z, bst.w};
    uint cnt[4] = {0u, 0u, 0u, 0u};

    for (int r = 0; r < 64; r++) {
        const int row = r0 + r;
        const float4 v = ((const float4*)(in + (size_t)row * UNITS))[c4];
        const uint b1 = s_b1[r];
        const float vv[4] = {v.x, v.y, v.z, v.w};
        float o[4];
        uint k[4];
        bool f[4];
        #pragma unroll
        for (int c = 0; c < 4; c++) {
            k[c] = tokey(vv[c] * bb[c]);
            const uint kb = k[c] >> 20;
            const bool keep = kb >= b1;       // provisional win (losers fixed later)
            o[c] = keep ? vv[c] : 0.0f;
            cnt[c] += keep ? 1u : 0u;
            f[c] = (kb == b1);
        }
        ((float4*)(out + (size_t)row * UNITS))[c4] = make_float4(o[0], o[1], o[2], o[3]);

        u64 bal[4];
        #pragma unroll
        for (int c = 0; c < 4; c++) bal[c] = __ballot(f[c]);
        uint wtot = (uint)(__popcll(bal[0]) + __popcll(bal[1]) + __popcll(bal[2]) + __popcll(bal[3]));
        if (wtot) {   // wave-uniform
            uint sbase = 0;
            if (lane == 0) sbase = atomicAdd(&candcnt[row * 16], wtot);
            sbase = (uint)__shfl((int)sbase, 0);
            uint cum = 0;
            #pragma unroll
            for (int c = 0; c < 4; c++) {
                if (f[c]) {
                    uint pos = sbase + cum + (uint)__popcll(bal[c] & ltmask);
                    if (pos < CAP) {
                        candkey[(size_t)row * CAP + pos] = k[c];
                        candidx[(size_t)row * CAP + pos] = u0 + (uint)c;
                    }
                }
                cum += (uint)__popcll(bal[c]);
            }
        }
    }
    ((uint4*)(cnt4 + (size_t)blockIdx.y * UNITS))[c4] = make_uint4(cnt[0], cnt[1], cnt[2], cnt[3]);
}

// 1024-bin suffix-scan crossing finder (all 256 threads call).
__device__ __forceinline__ void find_cross_1024(const uint* __restrict__ h, uint* ts,
                                                uint need, uint* out3, int tid) {
    uint binsum[4];
    uint segsum = 0;
    const int b0 = tid * 4;
    for (int i = 0; i < 4; i++) { binsum[i] = h[b0 + i]; segsum += binsum[i]; }
    ts[tid] = segsum;
    __syncthreads();
    for (int off = 1; off < 256; off <<= 1) {
        uint v = (tid + off < 256) ? ts[tid + off] : 0u;
        __syncthreads();
        ts[tid] += v;
        __syncthreads();
    }
    uint cum = ts[tid] - segsum;
    for (int i = 3; i >= 0; i--) {
        uint hb = binsum[i];
        uint c2 = cum + hb;
        if (cum < need && c2 >= need) { out3[0] = (uint)(b0 + i); out3[1] = cum; out3[2] = hb; }
        cum = c2;
    }
    __syncthreads();
}

// Per row (compute-only, no scattered I/O): exact 32-bit threshold key via
// 20-bit LDS radix select + tie-winner list (lowest-index-first).
__global__ __launch_bounds__(256) void selectfix_kernel(const uint* __restrict__ candcnt,
                                                        const uint* __restrict__ candkey,
                                                        const uint* __restrict__ candidx,
                                                        const uint* __restrict__ prior_a,
                                                        uint* __restrict__ tk_a,
                                                        uint* __restrict__ eqinfo,
                                                        uint* __restrict__ ndeq_a,
                                                        uint* __restrict__ eqwin) {
    __shared__ uint kbuf[CAP];
    __shared__ uint h1[1024];
    __shared__ uint ts[256];
    __shared__ uint sh[6];
    __shared__ uint eqlist[EQLDS];
    __shared__ uint ecnt_s, wn_s;
    const int row = blockIdx.x;
    const int tid = threadIdx.x;
    const uint n = min(candcnt[row * 16], (uint)CAP);
    const uint needbin = K_SEL - prior_a[row];
    const uint* ck = candkey + (size_t)row * CAP;
    const uint* ci = candidx + (size_t)row * CAP;

    uint tk = 0, mode = MODE_ALL, ndq = 0;

    if (needbin < n) {
        for (uint i = tid; i < n; i += 256) kbuf[i] = ck[i];
        // round 1: bits 19:10
        for (int i = tid; i < 1024; i += 256) h1[i] = 0u;
        __syncthreads();
        for (uint i = tid; i < n; i += 256) atomicAdd(&h1[(kbuf[i] >> 10) & 1023u], 1u);
        __syncthreads();
        find_cross_1024(h1, ts, needbin, sh, tid);
        const uint b2 = sh[0];
        const uint need2 = needbin - sh[1];
        __syncthreads();
        // round 2: bits 9:0 within crossing bin
        for (int i = tid; i < 1024; i += 256) h1[i] = 0u;
        __syncthreads();
        for (uint i = tid; i < n; i += 256)
            if (((kbuf[i] >> 10) & 1023u) == b2) atomicAdd(&h1[kbuf[i] & 1023u], 1u);
        __syncthreads();
        find_cross_1024(h1, ts, need2, sh + 3, tid);
        const uint b3 = sh[3];
        tk = (kbuf[0] & 0xFFF00000u) | (b2 << 10) | b3;   // shared 12-bit prefix
        const uint nd_eq = need2 - sh[4];                  // eq-key elements to take
        const uint eqc   = sh[5];                          // eq-key elements present
        ndq = nd_eq;

        if (eqc == nd_eq) {
            mode = MODE_ALL;   // every eq-key element wins
        } else if (eqc <= (uint)EQLDS && nd_eq <= (uint)EQWIN) {
            if (tid == 0) { ecnt_s = 0u; wn_s = 0u; }
            __syncthreads();
            for (uint i = tid; i < n; i += 256)
                if (kbuf[i] == tk) { uint p = atomicAdd(&ecnt_s, 1u); eqlist[p] = ci[i]; }
            __syncthreads();
            const uint ec = ecnt_s;
            for (uint t = tid; t < ec; t += 256) {
                const uint my = eqlist[t];
                uint rank = 0;
                for (uint j = 0; j < ec; j++) rank += (eqlist[j] < my) ? 1u : 0u;
                if (rank < nd_eq) {           // lowest-index-first winners
                    uint p = atomicAdd(&wn_s, 1u);
                    eqwin[(size_t)row * EQWIN + p] = my;
                }
            }
            __syncthreads();
            mode = wn_s;                       // == nd_eq
        } else {
            mode = MODE_SCAN;                  // bulletproof fallback (never in practice)
        }
    }

    if (tid == 0) { tk_a[row] = tk; eqinfo[row] = mode; ndeq_a[row] = ndq; }
}

// One candidate per thread: zero the losing candidates and decrement their counts.
__global__ __launch_bounds__(512) void fixwrite_kernel(const uint* __restrict__ candcnt,
                                                       const uint* __restrict__ candkey,
                                                       const uint* __restrict__ candidx,
                                                       const uint* __restrict__ tk_a,
                                                       const uint* __restrict__ eqinfo,
                                                       const uint* __restrict__ ndeq_a,
                                                       const uint* __restrict__ eqwin,
                                                       float* __restrict__ out,
                                                       uint* __restrict__ cnt4) {
    const int row = blockIdx.y;
    const uint n = min(candcnt[row * 16], (uint)CAP);
    const uint i = blockIdx.x * 512 + threadIdx.x;
    if (i >= n) return;
    const uint k = candkey[(size_t)row * CAP + i];
    const uint tk = tk_a[row];
    bool win;
    if (k > tk) {
        win = true;
    } else if (k < tk) {
        win = false;
    } else {
        const uint m = eqinfo[row];
        if (m == MODE_ALL) {
            win = true;
        } else if (m == MODE_SCAN) {           // exact rank by global scan (never in practice)
            const uint my = candidx[(size_t)row * CAP + i];
            uint rank = 0;
            for (uint j = 0; j < n; j++)
                if (candkey[(size_t)row * CAP + j] == tk &&
                    candidx[(size_t)row * CAP + j] < my) rank++;
            win = rank < ndeq_a[row];
        } else {
            const uint my = candidx[(size_t)row * CAP + i];
            win = false;
            for (uint j = 0; j < m; j++)
                if (eqwin[(size_t)row * EQWIN + j] == my) { win = true; break; }
        }
    }
    if (!win) {
        const uint idx = candidx[(size_t)row * CAP + i];
        out[(size_t)row * UNITS + idx] = 0.0f;
        atomicAdd(&cnt4[idx], 0xFFFFFFFFu);   // -1; mod-2^32 sum stays exact
    }
}

__global__ void duty_kernel(const float* __restrict__ duty, const uint* __restrict__ cnt4,
                            float* __restrict__ out_duty) {
    int u = blockIdx.x * 256 + threadIdx.x;
    const float C1 = (float)(1.0 - 1.0 / 1000.0);
    const float C2 = (float)(1.0 / 1000.0);
    uint c = cnt4[u] + cnt4[UNITS + u] + cnt4[2 * UNITS + u] + cnt4[3 * UNITS + u];
    float cur = (float)c * (1.0f / 256.0f);   // exact
    out_duty[u] = __fadd_rn(__fmul_rn(C1, duty[u]), __fmul_rn(C2, cur));
}

extern "C" void kernel_launch(void* const* d_in, const int* in_sizes, int n_in,
                              void* d_out, int out_size, void* d_ws, size_t ws_size,
                              hipStream_t stream) {
    const float* inputs = (const float*)d_in[0];
    const float* duty   = (const float*)d_in[1];
    float* out      = (float*)d_out;
    float* out_duty = out + (size_t)BATCH * UNITS;

    char* ws = (char*)d_ws;
    float* boost  = (float*)(ws + 0);
    uint* ghist   = (uint*)(ws + 524288);
    uint* candcnt = (uint*)(ws + 17301504);
    uint* b1_a    = (uint*)(ws + 17317888);
    uint* prior_a = (uint*)(ws + 17318912);
    uint* tk_a    = (uint*)(ws + 17319936);
    uint* eqinfo  = (uint*)(ws + 17320960);
    uint* ndeq_a  = (uint*)(ws + 17321984);
    uint* eqwin   = (uint*)(ws + 17323008);
    uint* candkey = (uint*)(ws + 17585152);
    uint* candidx = (uint*)(ws + 25973760);
    uint* cnt4    = (uint*)(ws + 34362368);

    hipMemsetAsync(candcnt, 0, 16384, stream);

    boost_kernel<<<UNITS / 256, 256, 0, stream>>>(duty, boost);

    hist_kernel<<<dim3(NCHUNK, BATCH), 256, 0, stream>>>(inputs, boost, ghist);

    scan_kernel<<<BATCH, 256, 0, stream>>>(ghist, b1_a, prior_a);

    apply_kernel<<<dim3(UNITS / 1024, 4), 256, 0, stream>>>(inputs, boost, b1_a, out, cnt4,
                                                            candcnt, candkey, candidx);

    selectfix_kernel<<<BATCH, 256, 0, stream>>>(candcnt, candkey, candidx, prior_a,
                                                tk_a, eqinfo, ndeq_a, eqwin);

    fixwrite_kernel<<<dim3(CAP / 512, BATCH), 512, 0, stream>>>(candcnt, candkey, candidx,
                                                                tk_a, eqinfo, ndeq_a, eqwin,
                                                                out, cnt4);

    duty_kernel<<<UNITS / 256, 256, 0, stream>>>(duty, cnt4, out_duty);
}

// Round 6
// 141.550 us; speedup vs baseline: 8.7421x; 1.1035x over previous
//
#include <hip/hip_runtime.h>

typedef unsigned int uint;
typedef unsigned long long u64;

#define K_SEL   13107u
#define BATCH   256
#define UNITS   131072
#define HB      4096      // 12-bit first-stage bins
#define CAP     8192      // candidate capacity per row (expect ~2800)
#define NCHUNK  4
#define NRG     16        // row-groups in apply (16 rows each)
#define EQLDS   2048      // max eq-key elements handled in LDS
#define EQWIN   256       // max tie winners stored per row

#define MODE_ALL  0xFFFFFFFFu
#define MODE_SCAN 0xFFFFFFFEu

// ---------- workspace layout (bytes) ----------
// 0         boost   [131072] f32              524288
// 524288    ghist   [4][256][4096] u32      16777216  (fully rewritten)
// 17301504  candcnt [256][16] u32              16384  (memset)
// 17317888  b1      [256] u32                   1024
// 17318912  prior   [256] u32                   1024
// 17319936  tk_a    [256] u32                   1024
// 17320960  eqinfo  [256] u32                   1024
// 17321984  ndeq_a  [256] u32                   1024
// 17323008  eqwin   [256][EQWIN] u32          262144
// 17585152  candkey [256][CAP] u32           8388608
// 25973760  candidx [256][CAP] u32           8388608
// 34362368  cnt4    [16][131072] u32         8388608
// total 42750976 (~40.8 MB)

__device__ __forceinline__ uint tokey(float f) {
    uint b = __float_as_uint(f);
    return b ^ ((uint)((int)b >> 31) | 0x80000000u);
}

__global__ void boost_kernel(const float* __restrict__ duty, float* __restrict__ boost) {
    int u = blockIdx.x * 256 + threadIdx.x;
    const float TARGET = (float)(13107.0 / 131072.0);
    float t = __fsub_rn(TARGET, duty[u]);
    boost[u] = (float)exp((double)t);   // correctly-rounded f32, matches np.exp
}

// Streaming histogram: per-(chunk,row) private 4096-bin slab, NO global atomics.
// 512 threads (8 waves) -> 4 blocks/CU * 8 waves = full occupancy (LDS 32KB/block).
__global__ __launch_bounds__(512) void hist_kernel(const float* __restrict__ in,
                                                   const float* __restrict__ boost,
                                                   uint* __restrict__ ghist) {
    __shared__ uint lh[2][HB];
    const int row = blockIdx.y;
    uint* h = lh[(threadIdx.x >> 7) & 1];
    for (int i = threadIdx.x; i < 2 * HB; i += 512) ((uint*)lh)[i] = 0u;
    __syncthreads();

    const float4* inp = (const float4*)(in + (size_t)row * UNITS) + (size_t)blockIdx.x * 8192;
    const float4* bst = (const float4*)boost + (size_t)blockIdx.x * 8192;
    for (int i = 0; i < 16; i++) {
        int idx = i * 512 + threadIdx.x;
        float4 a = inp[idx];
        float4 b = bst[idx];
        atomicAdd(&h[tokey(a.x * b.x) >> 20], 1u);
        atomicAdd(&h[tokey(a.y * b.y) >> 20], 1u);
        atomicAdd(&h[tokey(a.z * b.z) >> 20], 1u);
        atomicAdd(&h[tokey(a.w * b.w) >> 20], 1u);
    }
    __syncthreads();
    uint* gh = ghist + ((size_t)blockIdx.x * BATCH + row) * HB;
    for (int i = threadIdx.x; i < HB; i += 512) gh[i] = lh[0][i] + lh[1][i];
}

// Per row: sum 4 slabs, find crossing bin b1 and prior (count in higher bins).
__global__ __launch_bounds__(256) void scan_kernel(const uint* __restrict__ ghist,
                                                   uint* __restrict__ b1_a,
                                                   uint* __restrict__ prior_a) {
    __shared__ uint h[HB];
    __shared__ uint ts[256];
    __shared__ uint bc[2];
    const int row = blockIdx.x;
    const int tid = threadIdx.x;
    for (int i = tid; i < HB; i += 256) {
        uint s = 0;
        for (int c = 0; c < NCHUNK; c++) s += ghist[((size_t)c * BATCH + row) * HB + i];
        h[i] = s;
    }
    __syncthreads();

    const int b0 = tid * 16;
    uint binsum[16];
    uint segsum = 0;
    for (int i = 0; i < 16; i++) { binsum[i] = h[b0 + i]; segsum += binsum[i]; }
    ts[tid] = segsum;
    __syncthreads();
    for (int off = 1; off < 256; off <<= 1) {
        uint v = (tid + off < 256) ? ts[tid + off] : 0u;
        __syncthreads();
        ts[tid] += v;
        __syncthreads();
    }
    uint cum = ts[tid] - segsum;
    for (int i = 15; i >= 0; i--) {
        uint hb = binsum[i];
        uint c2 = cum + hb;
        if (cum < K_SEL && c2 >= K_SEL) { bc[0] = (uint)(b0 + i); bc[1] = cum; }
        cum = c2;
    }
    __syncthreads();
    if (tid == 0) { b1_a[row] = bc[0]; prior_a[row] = bc[1]; }
}

// Streaming apply: at-or-above crossing bin keeps value & counts as win;
// crossing-bin elements compacted (ballot + one atomic per wave per row).
// 16 rows/block -> 2048 blocks -> full occupancy to hide atomic latency.
__global__ __launch_bounds__(256) void apply_kernel(const float* __restrict__ in,
                                                    const float* __restrict__ boost,
                                                    const uint* __restrict__ b1_a,
                                                    float* __restrict__ out,
                                                    uint* __restrict__ cnt4,
                                                    uint* __restrict__ candcnt,
                                                    uint* __restrict__ candkey,
                                                    uint* __restrict__ candidx) {
    __shared__ uint s_b1[16];
    const int r0 = blockIdx.y * 16;
    if (threadIdx.x < 16) s_b1[threadIdx.x] = b1_a[r0 + threadIdx.x];
    __syncthreads();

    const int lane = threadIdx.x & 63;
    const u64 ltmask = ((u64)1 << lane) - 1;
    const int c4 = blockIdx.x * 256 + threadIdx.x;
    const float4 bst = ((const float4*)boost)[c4];
    const uint u0 = (uint)c4 * 4u;
    const float bb[4] = {bst.x, bst.y, bst.z, bst.w};
    uint cnt[4] = {0u, 0u, 0u, 0u};

    for (int r = 0; r < 16; r++) {
        const int row = r0 + r;
        const float4 v = ((const float4*)(in + (size_t)row * UNITS))[c4];
        const uint b1 = s_b1[r];
        const float vv[4] = {v.x, v.y, v.z, v.w};
        float o[4];
        uint k[4];
        bool f[4];
        #pragma unroll
        for (int c = 0; c < 4; c++) {
            k[c] = tokey(vv[c] * bb[c]);
            const uint kb = k[c] >> 20;
            const bool keep = kb >= b1;       // provisional win (losers fixed later)
            o[c] = keep ? vv[c] : 0.0f;
            cnt[c] += keep ? 1u : 0u;
            f[c] = (kb == b1);
        }
        ((float4*)(out + (size_t)row * UNITS))[c4] = make_float4(o[0], o[1], o[2], o[3]);

        u64 bal[4];
        #pragma unroll
        for (int c = 0; c < 4; c++) bal[c] = __ballot(f[c]);
        uint wtot = (uint)(__popcll(bal[0]) + __popcll(bal[1]) + __popcll(bal[2]) + __popcll(bal[3]));
        if (wtot) {   // wave-uniform
            uint sbase = 0;
            if (lane == 0) sbase = atomicAdd(&candcnt[row * 16], wtot);
            sbase = (uint)__shfl((int)sbase, 0);
            uint cum = 0;
            #pragma unroll
            for (int c = 0; c < 4; c++) {
                if (f[c]) {
                    uint pos = sbase + cum + (uint)__popcll(bal[c] & ltmask);
                    if (pos < CAP) {
                        candkey[(size_t)row * CAP + pos] = k[c];
                        candidx[(size_t)row * CAP + pos] = u0 + (uint)c;
                    }
                }
                cum += (uint)__popcll(bal[c]);
            }
        }
    }
    ((uint4*)(cnt4 + (size_t)blockIdx.y * UNITS))[c4] = make_uint4(cnt[0], cnt[1], cnt[2], cnt[3]);
}

// 1024-bin suffix-scan crossing finder (all 256 threads call).
__device__ __forceinline__ void find_cross_1024(const uint* __restrict__ h, uint* ts,
                                                uint need, uint* out3, int tid) {
    uint binsum[4];
    uint segsum = 0;
    const int b0 = tid * 4;
    for (int i = 0; i < 4; i++) { binsum[i] = h[b0 + i]; segsum += binsum[i]; }
    ts[tid] = segsum;
    __syncthreads();
    for (int off = 1; off < 256; off <<= 1) {
        uint v = (tid + off < 256) ? ts[tid + off] : 0u;
        __syncthreads();
        ts[tid] += v;
        __syncthreads();
    }
    uint cum = ts[tid] - segsum;
    for (int i = 3; i >= 0; i--) {
        uint hb = binsum[i];
        uint c2 = cum + hb;
        if (cum < need && c2 >= need) { out3[0] = (uint)(b0 + i); out3[1] = cum; out3[2] = hb; }
        cum = c2;
    }
    __syncthreads();
}

// Per row (compute-only): exact 32-bit threshold + tie-winner list.
__global__ __launch_bounds__(256) void selectfix_kernel(const uint* __restrict__ candcnt,
                                                        const uint* __restrict__ candkey,
                                                        const uint* __restrict__ candidx,
                                                        const uint* __restrict__ prior_a,
                                                        uint* __restrict__ tk_a,
                                                        uint* __restrict__ eqinfo,
                                                        uint* __restrict__ ndeq_a,
                                                        uint* __restrict__ eqwin) {
    __shared__ uint kbuf[CAP];
    __shared__ uint h1[1024];
    __shared__ uint ts[256];
    __shared__ uint sh[6];
    __shared__ uint eqlist[EQLDS];
    __shared__ uint ecnt_s, wn_s;
    const int row = blockIdx.x;
    const int tid = threadIdx.x;
    const uint n = min(candcnt[row * 16], (uint)CAP);
    const uint needbin = K_SEL - prior_a[row];
    const uint* ck = candkey + (size_t)row * CAP;
    const uint* ci = candidx + (size_t)row * CAP;

    uint tk = 0, mode = MODE_ALL, ndq = 0;

    if (needbin < n) {
        for (uint i = tid; i < n; i += 256) kbuf[i] = ck[i];
        for (int i = tid; i < 1024; i += 256) h1[i] = 0u;
        __syncthreads();
        for (uint i = tid; i < n; i += 256) atomicAdd(&h1[(kbuf[i] >> 10) & 1023u], 1u);
        __syncthreads();
        find_cross_1024(h1, ts, needbin, sh, tid);
        const uint b2 = sh[0];
        const uint need2 = needbin - sh[1];
        __syncthreads();
        for (int i = tid; i < 1024; i += 256) h1[i] = 0u;
        __syncthreads();
        for (uint i = tid; i < n; i += 256)
            if (((kbuf[i] >> 10) & 1023u) == b2) atomicAdd(&h1[kbuf[i] & 1023u], 1u);
        __syncthreads();
        find_cross_1024(h1, ts, need2, sh + 3, tid);
        const uint b3 = sh[3];
        tk = (kbuf[0] & 0xFFF00000u) | (b2 << 10) | b3;   // shared 12-bit prefix
        const uint nd_eq = need2 - sh[4];
        const uint eqc   = sh[5];
        ndq = nd_eq;

        if (eqc == nd_eq) {
            mode = MODE_ALL;
        } else if (eqc <= (uint)EQLDS && nd_eq <= (uint)EQWIN) {
            if (tid == 0) { ecnt_s = 0u; wn_s = 0u; }
            __syncthreads();
            for (uint i = tid; i < n; i += 256)
                if (kbuf[i] == tk) { uint p = atomicAdd(&ecnt_s, 1u); eqlist[p] = ci[i]; }
            __syncthreads();
            const uint ec = ecnt_s;
            for (uint t = tid; t < ec; t += 256) {
                const uint my = eqlist[t];
                uint rank = 0;
                for (uint j = 0; j < ec; j++) rank += (eqlist[j] < my) ? 1u : 0u;
                if (rank < nd_eq) {
                    uint p = atomicAdd(&wn_s, 1u);
                    eqwin[(size_t)row * EQWIN + p] = my;
                }
            }
            __syncthreads();
            mode = wn_s;                       // == nd_eq
        } else {
            mode = MODE_SCAN;                  // bulletproof fallback
        }
    }

    if (tid == 0) { tk_a[row] = tk; eqinfo[row] = mode; ndeq_a[row] = ndq; }
}

// One candidate per thread: zero losing candidates, decrement their counts.
__global__ __launch_bounds__(512) void fixwrite_kernel(const uint* __restrict__ candcnt,
                                                       const uint* __restrict__ candkey,
                                                       const uint* __restrict__ candidx,
                                                       const uint* __restrict__ tk_a,
                                                       const uint* __restrict__ eqinfo,
                                                       const uint* __restrict__ ndeq_a,
                                                       const uint* __restrict__ eqwin,
                                                       float* __restrict__ out,
                                                       uint* __restrict__ cnt4) {
    const int row = blockIdx.y;
    const uint n = min(candcnt[row * 16], (uint)CAP);
    const uint i = blockIdx.x * 512 + threadIdx.x;
    if (i >= n) return;
    const uint k = candkey[(size_t)row * CAP + i];
    const uint tk = tk_a[row];
    bool win;
    if (k > tk) {
        win = true;
    } else if (k < tk) {
        win = false;
    } else {
        const uint m = eqinfo[row];
        if (m == MODE_ALL) {
            win = true;
        } else if (m == MODE_SCAN) {
            const uint my = candidx[(size_t)row * CAP + i];
            uint rank = 0;
            for (uint j = 0; j < n; j++)
                if (candkey[(size_t)row * CAP + j] == tk &&
                    candidx[(size_t)row * CAP + j] < my) rank++;
            win = rank < ndeq_a[row];
        } else {
            const uint my = candidx[(size_t)row * CAP + i];
            win = false;
            for (uint j = 0; j < m; j++)
                if (eqwin[(size_t)row * EQWIN + j] == my) { win = true; break; }
        }
    }
    if (!win) {
        const uint idx = candidx[(size_t)row * CAP + i];
        out[(size_t)row * UNITS + idx] = 0.0f;
        atomicAdd(&cnt4[idx], 0xFFFFFFFFu);   // -1; mod-2^32 sum stays exact
    }
}

__global__ void duty_kernel(const float* __restrict__ duty, const uint* __restrict__ cnt4,
                            float* __restrict__ out_duty) {
    int u = blockIdx.x * 256 + threadIdx.x;
    const float C1 = (float)(1.0 - 1.0 / 1000.0);
    const float C2 = (float)(1.0 / 1000.0);
    uint c = 0;
    #pragma unroll
    for (int s = 0; s < NRG; s++) c += cnt4[(size_t)s * UNITS + u];
    float cur = (float)c * (1.0f / 256.0f);   // exact
    out_duty[u] = __fadd_rn(__fmul_rn(C1, duty[u]), __fmul_rn(C2, cur));
}

extern "C" void kernel_launch(void* const* d_in, const int* in_sizes, int n_in,
                              void* d_out, int out_size, void* d_ws, size_t ws_size,
                              hipStream_t stream) {
    const float* inputs = (const float*)d_in[0];
    const float* duty   = (const float*)d_in[1];
    float* out      = (float*)d_out;
    float* out_duty = out + (size_t)BATCH * UNITS;

    char* ws = (char*)d_ws;
    float* boost  = (float*)(ws + 0);
    uint* ghist   = (uint*)(ws + 524288);
    uint* candcnt = (uint*)(ws + 17301504);
    uint* b1_a    = (uint*)(ws + 17317888);
    uint* prior_a = (uint*)(ws + 17318912);
    uint* tk_a    = (uint*)(ws + 17319936);
    uint* eqinfo  = (uint*)(ws + 17320960);
    uint* ndeq_a  = (uint*)(ws + 17321984);
    uint* eqwin   = (uint*)(ws + 17323008);
    uint* candkey = (uint*)(ws + 17585152);
    uint* candidx = (uint*)(ws + 25973760);
    uint* cnt4    = (uint*)(ws + 34362368);

    hipMemsetAsync(candcnt, 0, 16384, stream);

    boost_kernel<<<UNITS / 256, 256, 0, stream>>>(duty, boost);

    hist_kernel<<<dim3(NCHUNK, BATCH), 512, 0, stream>>>(inputs, boost, ghist);

    scan_kernel<<<BATCH, 256, 0, stream>>>(ghist, b1_a, prior_a);

    apply_kernel<<<dim3(UNITS / 1024, NRG), 256, 0, stream>>>(inputs, boost, b1_a, out, cnt4,
                                                              candcnt, candkey, candidx);

    selectfix_kernel<<<BATCH, 256, 0, stream>>>(candcnt, candkey, candidx, prior_a,
                                                tk_a, eqinfo, ndeq_a, eqwin);

    fixwrite_kernel<<<dim3(CAP / 512, BATCH), 512, 0, stream>>>(candcnt, candkey, candidx,
                                                                tk_a, eqinfo, ndeq_a, eqwin,
                                                                out, cnt4);

    duty_kernel<<<UNITS / 256, 256, 0, stream>>>(duty, cnt4, out_duty);
}

// Round 8
// 123.359 us; speedup vs baseline: 10.0312x; 1.1475x over previous
//
#include <hip/hip_runtime.h>

typedef unsigned int uint;
typedef unsigned long long u64;
typedef float f32x4 __attribute__((ext_vector_type(4)));

#define K_SEL   13107u
#define BATCH   256
#define UNITS   131072
#define HB      4096      // 12-bit first-stage bins
#define CAP     8192      // candidate capacity per row (expect ~2800)
#define NCHUNK  4
#define NRG     16        // row-groups in apply (16 rows each)
#define EQLDS   2048      // max eq-key elements handled in LDS
#define EQWIN   256       // max tie winners

#define MODE_ALL  0xFFFFFFFFu
#define MODE_SCAN 0xFFFFFFFEu

// ---------- workspace layout (bytes) ----------
// 0         boost   [131072] f32              524288
// 524288    ghist   [4][256][4096] u32      16777216  (fully rewritten)
// 17301504  candcnt [256][16] u32              16384  (zeroed by boost_kernel)
// 17317888  b1      [256] u32                   1024
// 17318912  prior   [256] u32                   1024
// 17319936  candkey [256][CAP] u32           8388608
// 25708544  candidx [256][CAP] u32           8388608
// 34097152  cnt4    [16][131072] u32         8388608
// total 42485760 (~40.5 MB)

__device__ __forceinline__ uint tokey(float f) {
    uint b = __float_as_uint(f);
    return b ^ ((uint)((int)b >> 31) | 0x80000000u);
}

// Also zeroes candcnt (removes a separate memset dispatch).
__global__ void boost_kernel(const float* __restrict__ duty, float* __restrict__ boost,
                             uint* __restrict__ candcnt) {
    int u = blockIdx.x * 256 + threadIdx.x;
    const float TARGET = (float)(13107.0 / 131072.0);
    float t = __fsub_rn(TARGET, duty[u]);
    boost[u] = (float)exp((double)t);   // correctly-rounded f32, matches np.exp
    if (u < BATCH * 16) candcnt[u] = 0u;
}

// Streaming histogram: per-(chunk,row) private 4096-bin slab, NO global atomics.
// 512 threads (8 waves), LDS 32KB -> 4 blocks/CU, 32 waves/CU.
__global__ __launch_bounds__(512) void hist_kernel(const float* __restrict__ in,
                                                   const float* __restrict__ boost,
                                                   uint* __restrict__ ghist) {
    __shared__ uint lh[2][HB];
    const int row = blockIdx.y;
    uint* h = lh[(threadIdx.x >> 7) & 1];
    for (int i = threadIdx.x; i < 2 * HB; i += 512) ((uint*)lh)[i] = 0u;
    __syncthreads();

    const float4* inp = (const float4*)(in + (size_t)row * UNITS) + (size_t)blockIdx.x * 8192;
    const float4* bst = (const float4*)boost + (size_t)blockIdx.x * 8192;
    for (int i = 0; i < 16; i++) {
        int idx = i * 512 + threadIdx.x;
        float4 a = inp[idx];
        float4 b = bst[idx];
        atomicAdd(&h[tokey(a.x * b.x) >> 20], 1u);
        atomicAdd(&h[tokey(a.y * b.y) >> 20], 1u);
        atomicAdd(&h[tokey(a.z * b.z) >> 20], 1u);
        atomicAdd(&h[tokey(a.w * b.w) >> 20], 1u);
    }
    __syncthreads();
    uint* gh = ghist + ((size_t)blockIdx.x * BATCH + row) * HB;
    for (int i = threadIdx.x; i < HB; i += 512) gh[i] = lh[0][i] + lh[1][i];
}

// Per row: sum 4 slabs, find crossing bin b1 and prior (count in higher bins).
__global__ __launch_bounds__(256) void scan_kernel(const uint* __restrict__ ghist,
                                                   uint* __restrict__ b1_a,
                                                   uint* __restrict__ prior_a) {
    __shared__ uint h[HB];
    __shared__ uint ts[256];
    __shared__ uint bc[2];
    const int row = blockIdx.x;
    const int tid = threadIdx.x;
    for (int i = tid; i < HB; i += 256) {
        uint s = 0;
        for (int c = 0; c < NCHUNK; c++) s += ghist[((size_t)c * BATCH + row) * HB + i];
        h[i] = s;
    }
    __syncthreads();

    const int b0 = tid * 16;
    uint binsum[16];
    uint segsum = 0;
    for (int i = 0; i < 16; i++) { binsum[i] = h[b0 + i]; segsum += binsum[i]; }
    ts[tid] = segsum;
    __syncthreads();
    for (int off = 1; off < 256; off <<= 1) {
        uint v = (tid + off < 256) ? ts[tid + off] : 0u;
        __syncthreads();
        ts[tid] += v;
        __syncthreads();
    }
    uint cum = ts[tid] - segsum;
    for (int i = 15; i >= 0; i--) {
        uint hb = binsum[i];
        uint c2 = cum + hb;
        if (cum < K_SEL && c2 >= K_SEL) { bc[0] = (uint)(b0 + i); bc[1] = cum; }
        cum = c2;
    }
    __syncthreads();
    if (tid == 0) { b1_a[row] = bc[0]; prior_a[row] = bc[1]; }
}

// Streaming apply: at-or-above crossing bin keeps value & counts as win;
// crossing-bin elements compacted (ballot + one atomic per wave per row).
// out written non-temporally (never re-read) to keep in[] resident in L2/L3.
__global__ __launch_bounds__(256) void apply_kernel(const float* __restrict__ in,
                                                    const float* __restrict__ boost,
                                                    const uint* __restrict__ b1_a,
                                                    float* __restrict__ out,
                                                    uint* __restrict__ cnt4,
                                                    uint* __restrict__ candcnt,
                                                    uint* __restrict__ candkey,
                                                    uint* __restrict__ candidx) {
    __shared__ uint s_b1[16];
    const int r0 = blockIdx.y * 16;
    if (threadIdx.x < 16) s_b1[threadIdx.x] = b1_a[r0 + threadIdx.x];
    __syncthreads();

    const int lane = threadIdx.x & 63;
    const u64 ltmask = ((u64)1 << lane) - 1;
    const int c4 = blockIdx.x * 256 + threadIdx.x;
    const float4 bst = ((const float4*)boost)[c4];
    const uint u0 = (uint)c4 * 4u;
    const float bb[4] = {bst.x, bst.y, bst.z, bst.w};
    uint cnt[4] = {0u, 0u, 0u, 0u};

    for (int r = 0; r < 16; r++) {
        const int row = r0 + r;
        const float4 v = ((const float4*)(in + (size_t)row * UNITS))[c4];
        const uint b1 = s_b1[r];
        const float vv[4] = {v.x, v.y, v.z, v.w};
        float o[4];
        uint k[4];
        bool f[4];
        #pragma unroll
        for (int c = 0; c < 4; c++) {
            k[c] = tokey(vv[c] * bb[c]);
            const uint kb = k[c] >> 20;
            const bool keep = kb >= b1;       // provisional win (losers fixed later)
            o[c] = keep ? vv[c] : 0.0f;
            cnt[c] += keep ? 1u : 0u;
            f[c] = (kb == b1);
        }
        f32x4 ov = {o[0], o[1], o[2], o[3]};
        __builtin_nontemporal_store(ov, (f32x4*)(out + (size_t)row * UNITS) + c4);

        u64 bal[4];
        #pragma unroll
        for (int c = 0; c < 4; c++) bal[c] = __ballot(f[c]);
        uint wtot = (uint)(__popcll(bal[0]) + __popcll(bal[1]) + __popcll(bal[2]) + __popcll(bal[3]));
        if (wtot) {   // wave-uniform
            uint sbase = 0;
            if (lane == 0) sbase = atomicAdd(&candcnt[row * 16], wtot);
            sbase = (uint)__shfl((int)sbase, 0);
            uint cum = 0;
            #pragma unroll
            for (int c = 0; c < 4; c++) {
                if (f[c]) {
                    uint pos = sbase + cum + (uint)__popcll(bal[c] & ltmask);
                    if (pos < CAP) {
                        candkey[(size_t)row * CAP + pos] = k[c];
                        candidx[(size_t)row * CAP + pos] = u0 + (uint)c;
                    }
                }
                cum += (uint)__popcll(bal[c]);
            }
        }
    }
    ((uint4*)(cnt4 + (size_t)blockIdx.y * UNITS))[c4] = make_uint4(cnt[0], cnt[1], cnt[2], cnt[3]);
}

// 1024-bin suffix-scan crossing finder (all 256 threads call).
__device__ __forceinline__ void find_cross_1024(const uint* __restrict__ h, uint* ts,
                                                uint need, uint* out3, int tid) {
    uint binsum[4];
    uint segsum = 0;
    const int b0 = tid * 4;
    for (int i = 0; i < 4; i++) { binsum[i] = h[b0 + i]; segsum += binsum[i]; }
    ts[tid] = segsum;
    __syncthreads();
    for (int off = 1; off < 256; off <<= 1) {
        uint v = (tid + off < 256) ? ts[tid + off] : 0u;
        __syncthreads();
        ts[tid] += v;
        __syncthreads();
    }
    uint cum = ts[tid] - segsum;
    for (int i = 3; i >= 0; i--) {
        uint hb = binsum[i];
        uint c2 = cum + hb;
        if (cum < need && c2 >= need) { out3[0] = (uint)(b0 + i); out3[1] = cum; out3[2] = hb; }
        cum = c2;
    }
    __syncthreads();
}

// Fused per-row finisher: exact 32-bit threshold via 20-bit LDS radix select,
// lowest-index tie-break, then zero the losing candidates + decrement counts.
// Keys AND indices live in LDS; no global re-reads, no handoff buffers.
__global__ __launch_bounds__(256) void fix_kernel(const uint* __restrict__ candcnt,
                                                  const uint* __restrict__ candkey,
                                                  const uint* __restrict__ candidx,
                                                  const uint* __restrict__ prior_a,
                                                  float* __restrict__ out,
                                                  uint* __restrict__ cnt4) {
    __shared__ uint kbuf[CAP];
    __shared__ uint ibuf[CAP];
    __shared__ uint h1[1024];
    __shared__ uint ts[256];
    __shared__ uint sh[6];
    __shared__ uint eqlist[EQLDS];
    __shared__ uint wlist[EQWIN];
    __shared__ uint ecnt_s, wn_s;
    const int row = blockIdx.x;
    const int tid = threadIdx.x;
    const uint n = min(candcnt[row * 16], (uint)CAP);
    const uint needbin = K_SEL - prior_a[row];
    const uint* ck = candkey + (size_t)row * CAP;
    const uint* ci = candidx + (size_t)row * CAP;

    if (needbin >= n) return;   // every candidate wins; no losers to fix

    for (uint i = tid; i < n; i += 256) { kbuf[i] = ck[i]; ibuf[i] = ci[i]; }
    // round 1: bits 19:10
    for (int i = tid; i < 1024; i += 256) h1[i] = 0u;
    __syncthreads();
    for (uint i = tid; i < n; i += 256) atomicAdd(&h1[(kbuf[i] >> 10) & 1023u], 1u);
    __syncthreads();
    find_cross_1024(h1, ts, needbin, sh, tid);
    const uint b2 = sh[0];
    const uint need2 = needbin - sh[1];
    __syncthreads();
    // round 2: bits 9:0 within crossing bin
    for (int i = tid; i < 1024; i += 256) h1[i] = 0u;
    __syncthreads();
    for (uint i = tid; i < n; i += 256)
        if (((kbuf[i] >> 10) & 1023u) == b2) atomicAdd(&h1[kbuf[i] & 1023u], 1u);
    __syncthreads();
    find_cross_1024(h1, ts, need2, sh + 3, tid);
    const uint b3 = sh[3];
    const uint tk = (kbuf[0] & 0xFFF00000u) | (b2 << 10) | b3;   // shared 12-bit prefix
    const uint nd_eq = need2 - sh[4];
    const uint eqc   = sh[5];

    uint mode;
    if (eqc == nd_eq) {
        mode = MODE_ALL;
    } else if (eqc <= (uint)EQLDS && nd_eq <= (uint)EQWIN) {
        if (tid == 0) { ecnt_s = 0u; wn_s = 0u; }
        __syncthreads();
        for (uint i = tid; i < n; i += 256)
            if (kbuf[i] == tk) { uint p = atomicAdd(&ecnt_s, 1u); eqlist[p] = ibuf[i]; }
        __syncthreads();
        const uint ec = ecnt_s;
        for (uint t = tid; t < ec; t += 256) {
            const uint my = eqlist[t];
            uint rank = 0;
            for (uint j = 0; j < ec; j++) rank += (eqlist[j] < my) ? 1u : 0u;
            if (rank < nd_eq) {                 // lowest-index-first winners
                uint p = atomicAdd(&wn_s, 1u);
                wlist[p] = my;
            }
        }
        __syncthreads();
        mode = wn_s;                             // == nd_eq
    } else {
        mode = MODE_SCAN;                        // bulletproof fallback
        __syncthreads();
    }

    // zero losers, decrement their counts (mod-2^32 stays exact)
    for (uint i = tid; i < n; i += 256) {
        const uint k = kbuf[i];
        bool win;
        if (k > tk) {
            win = true;
        } else if (k < tk) {
            win = false;
        } else if (mode == MODE_ALL) {
            win = true;
        } else if (mode == MODE_SCAN) {
            const uint my = ibuf[i];
            uint rank = 0;
            for (uint j = 0; j < n; j++)
                if (kbuf[j] == tk && ibuf[j] < my) rank++;
            win = rank < nd_eq;
        } else {
            const uint my = ibuf[i];
            win = false;
            for (uint j = 0; j < mode; j++)
                if (wlist[j] == my) { win = true; break; }
        }
        if (!win) {
            const uint idx = ibuf[i];
            out[(size_t)row * UNITS + idx] = 0.0f;
            atomicAdd(&cnt4[idx], 0xFFFFFFFFu);   // -1
        }
    }
}

__global__ void duty_kernel(const float* __restrict__ duty, const uint* __restrict__ cnt4,
                            float* __restrict__ out_duty) {
    int u = blockIdx.x * 256 + threadIdx.x;
    const float C1 = (float)(1.0 - 1.0 / 1000.0);
    const float C2 = (float)(1.0 / 1000.0);
    uint c = 0;
    #pragma unroll
    for (int s = 0; s < NRG; s++) c += cnt4[(size_t)s * UNITS + u];
    float cur = (float)c * (1.0f / 256.0f);   // exact
    out_duty[u] = __fadd_rn(__fmul_rn(C1, duty[u]), __fmul_rn(C2, cur));
}

extern "C" void kernel_launch(void* const* d_in, const int* in_sizes, int n_in,
                              void* d_out, int out_size, void* d_ws, size_t ws_size,
                              hipStream_t stream) {
    const float* inputs = (const float*)d_in[0];
    const float* duty   = (const float*)d_in[1];
    float* out      = (float*)d_out;
    float* out_duty = out + (size_t)BATCH * UNITS;

    char* ws = (char*)d_ws;
    float* boost  = (float*)(ws + 0);
    uint* ghist   = (uint*)(ws + 524288);
    uint* candcnt = (uint*)(ws + 17301504);
    uint* b1_a    = (uint*)(ws + 17317888);
    uint* prior_a = (uint*)(ws + 17318912);
    uint* candkey = (uint*)(ws + 17319936);
    uint* candidx = (uint*)(ws + 25708544);
    uint* cnt4    = (uint*)(ws + 34097152);

    boost_kernel<<<UNITS / 256, 256, 0, stream>>>(duty, boost, candcnt);

    hist_kernel<<<dim3(NCHUNK, BATCH), 512, 0, stream>>>(inputs, boost, ghist);

    scan_kernel<<<BATCH, 256, 0, stream>>>(ghist, b1_a, prior_a);

    apply_kernel<<<dim3(UNITS / 1024, NRG), 256, 0, stream>>>(inputs, boost, b1_a, out, cnt4,
                                                              candcnt, candkey, candidx);

    fix_kernel<<<BATCH, 256, 0, stream>>>(candcnt, candkey, candidx, prior_a, out, cnt4);

    duty_kernel<<<UNITS / 256, 256, 0, stream>>>(duty, cnt4, out_duty);
}